// Round 3
// baseline (189.895 us; speedup 1.0000x reference)
//
#include <hip/hip_runtime.h>
#include <hip/hip_bf16.h>
#include <stdint.h>

typedef uint16_t u16;
typedef uint32_t u32;
typedef __attribute__((ext_vector_type(8))) short short8;   // 8 x bf16 (MFMA A/B frag)
typedef __attribute__((ext_vector_type(4))) float f32x4;    // MFMA C/D frag

#define LOG2E 1.44269504088896340736f

__device__ __forceinline__ u16 f2bf(float f) {
    u32 u = __builtin_bit_cast(u32, f);
    return (u16)((u + 0x7fffu + ((u >> 16) & 1u)) >> 16);   // RNE
}
__device__ __forceinline__ float bf2f(u16 h) {
    u32 u = ((u32)h) << 16;
    return __builtin_bit_cast(float, u);
}

// ---------------------------------------------------------------- convert f32 -> bf16 (8/thread)
__global__ __launch_bounds__(256)
void cvt_kernel(const float* __restrict__ src, u16* __restrict__ dst) {
    const size_t i = ((size_t)blockIdx.x * 256 + threadIdx.x) * 8;
    float4 a = *(const float4*)(src + i);
    float4 b = *(const float4*)(src + i + 4);
    uint4 o;
    o.x = (u32)f2bf(a.x) | ((u32)f2bf(a.y) << 16);
    o.y = (u32)f2bf(a.z) | ((u32)f2bf(a.w) << 16);
    o.z = (u32)f2bf(b.x) | ((u32)f2bf(b.y) << 16);
    o.w = (u32)f2bf(b.z) | ((u32)f2bf(b.w) << 16);
    *(uint4*)(dst + i) = o;
}

// ------------------------------------------- weights: transpose + bf16 (+ fold 0.125 into Wk,bk)
__global__ void wt_kernel(const float* __restrict__ Wq, const float* __restrict__ Wk,
                          const float* __restrict__ Wv, const float* __restrict__ Wo,
                          const float* __restrict__ bk, u16* __restrict__ WT,
                          float* __restrict__ bks) {
    const int wsel = blockIdx.y, k = blockIdx.x, n = threadIdx.x;
    const float* W = (wsel == 0) ? Wq : (wsel == 1) ? Wk : (wsel == 2) ? Wv : Wo;
    const float scale = (wsel == 1) ? 0.125f : 1.0f;
    WT[(size_t)wsel * 65536 + (size_t)n * 256 + k] = f2bf(W[(size_t)k * 256 + n] * scale);
    if (wsel == 1 && k == 0) bks[n] = bk[n] * 0.125f;
}

// ---------------------------------------------------------------- GEMM: C = A[M,256] @ W[256,256]
// BT is pre-transposed weights BT[n][k]. EPI=0: out bf16 = acc+bias. EPI=1: out f32 = resid + relu(acc+bias).
// EPI=1 may run IN-PLACE (outp == resid): per-index read-then-write by the same thread, no restrict.
// 128x128 tile, 4 waves (64x64 each), BK=64, XOR-swizzled LDS (conflict-free ds_read_b128).
// Staging: each thread owns a 64-byte half-row per buffer -> 4 x uint4 loads + 4 swizzled stores.
template<int EPI>
__global__ __launch_bounds__(256)
void gemm_kernel(const u16* __restrict__ A, const u16* __restrict__ BT,
                 const float* __restrict__ bias, const float* resid,
                 void* outp) {
    __shared__ u16 As[128 * 64];
    __shared__ u16 Bs[128 * 64];
    const int tid = threadIdx.x;
    const int w = tid >> 6, lane = tid & 63;
    const int g = lane >> 4, lo = lane & 15;
    const int rowB = blockIdx.x * 128;
    const int colB = blockIdx.y * 128;
    const int wr = (w >> 1) * 64, wc = (w & 1) * 64;

    const f32x4 fz = {0.f, 0.f, 0.f, 0.f};
    f32x4 acc[4][4];
#pragma unroll
    for (int m = 0; m < 4; ++m)
#pragma unroll
        for (int n = 0; n < 4; ++n) acc[m][n] = fz;

    const int srow = tid & 127;   // staging: row in tile
    const int shalf = tid >> 7;   // 0/1: which 32-elem (64-byte) half of the 64-wide K slab

#pragma unroll 1
    for (int kt = 0; kt < 4; ++kt) {
        const int k0 = kt * 64;
        __syncthreads();
        {
            const u16* ga = A + (size_t)(rowB + srow) * 256 + k0 + shalf * 32;
            uint4 a0 = *(const uint4*)ga;
            uint4 a1 = *(const uint4*)(ga + 8);
            uint4 a2 = *(const uint4*)(ga + 16);
            uint4 a3 = *(const uint4*)(ga + 24);
            const u16* gb = BT + (size_t)(colB + srow) * 256 + k0 + shalf * 32;
            uint4 b0 = *(const uint4*)gb;
            uint4 b1 = *(const uint4*)(gb + 8);
            uint4 b2 = *(const uint4*)(gb + 16);
            uint4 b3 = *(const uint4*)(gb + 24);
            const u32 sw = (u32)((srow & 7) << 4);
            const u32 ba = (u32)(srow * 128 + shalf * 64);
            *(uint4*)((char*)As + ((ba) ^ sw))      = a0;
            *(uint4*)((char*)As + ((ba + 16) ^ sw)) = a1;
            *(uint4*)((char*)As + ((ba + 32) ^ sw)) = a2;
            *(uint4*)((char*)As + ((ba + 48) ^ sw)) = a3;
            *(uint4*)((char*)Bs + ((ba) ^ sw))      = b0;
            *(uint4*)((char*)Bs + ((ba + 16) ^ sw)) = b1;
            *(uint4*)((char*)Bs + ((ba + 32) ^ sw)) = b2;
            *(uint4*)((char*)Bs + ((ba + 48) ^ sw)) = b3;
        }
        __syncthreads();
#pragma unroll
        for (int c = 0; c < 2; ++c) {
            short8 af[4], bfr[4];
#pragma unroll
            for (int m = 0; m < 4; ++m) {
                const int row = wr + m * 16 + lo;
                const u32 addr = (u32)(row * 128 + c * 64 + g * 16) ^ (u32)((row & 7) << 4);
                af[m] = *(const short8*)((char*)As + addr);
            }
#pragma unroll
            for (int n = 0; n < 4; ++n) {
                const int row = wc + n * 16 + lo;
                const u32 addr = (u32)(row * 128 + c * 64 + g * 16) ^ (u32)((row & 7) << 4);
                bfr[n] = *(const short8*)((char*)Bs + addr);
            }
#pragma unroll
            for (int m = 0; m < 4; ++m)
#pragma unroll
                for (int n = 0; n < 4; ++n)
                    acc[m][n] = __builtin_amdgcn_mfma_f32_16x16x32_bf16(af[m], bfr[n], acc[m][n], 0, 0, 0);
        }
    }

    float bv[4];
#pragma unroll
    for (int n = 0; n < 4; ++n) bv[n] = bias[colB + wc + n * 16 + lo];

    if (EPI == 0) {
        u16* out = (u16*)outp;
#pragma unroll
        for (int m = 0; m < 4; ++m)
#pragma unroll
            for (int r = 0; r < 4; ++r) {
                const size_t row = (size_t)(rowB + wr + m * 16 + g * 4 + r);
#pragma unroll
                for (int n = 0; n < 4; ++n)
                    out[row * 256 + colB + wc + n * 16 + lo] = f2bf(acc[m][n][r] + bv[n]);
            }
    } else {
        float* out = (float*)outp;
#pragma unroll
        for (int m = 0; m < 4; ++m)
#pragma unroll
            for (int r = 0; r < 4; ++r) {
                const size_t row = (size_t)(rowB + wr + m * 16 + g * 4 + r);
#pragma unroll
                for (int n = 0; n < 4; ++n) {
                    const size_t idx = row * 256 + colB + wc + n * 16 + lo;
                    out[idx] = resid[idx] + fmaxf(acc[m][n][r] + bv[n], 0.f);
                }
            }
    }
}

// ---------------------------------------------------------------- flash attention + q-residual
// grid (16 qtiles, H=4, B=8), 256 threads. Block: 128 q-rows; wave: 32 q-rows.
// Swapped QK^T: mfma(K, Q) -> S^T so key-reduction = 2 shfl_xor. kb is pre-scaled by 1/8.
__global__ __launch_bounds__(256)
void attn_kernel(const u16* __restrict__ qb, const u16* __restrict__ kb,
                 const u16* __restrict__ vb, float* __restrict__ Obuf) {
    __shared__ u16 Klds[64 * 64];    // [key][d], swizzled
    __shared__ u16 Vtlds[64 * 64];   // [d][key], swizzled
    __shared__ u16 Plds[4 * 32 * 64];// per-wave [q][key], swizzled
    const int tid = threadIdx.x;
    const int w = tid >> 6, lane = tid & 63;
    const int g = lane >> 4, lo = lane & 15;
    const int q0 = blockIdx.x * 128;
    const int h = blockIdx.y, b = blockIdx.z;
    const size_t hbase = (size_t)b * 2048 * 256 + (size_t)h * 64;

    short8 qf[2][2];   // [qn][c]  B-frags of Q
#pragma unroll
    for (int qn = 0; qn < 2; ++qn)
#pragma unroll
        for (int c = 0; c < 2; ++c) {
            const size_t row = (size_t)(q0 + w * 32 + qn * 16 + lo);
            qf[qn][c] = *(const short8*)&qb[hbase + row * 256 + c * 32 + g * 8];
        }

    const f32x4 fz = {0.f, 0.f, 0.f, 0.f};
    f32x4 oacc[2][4];
#pragma unroll
    for (int m = 0; m < 2; ++m)
#pragma unroll
        for (int n = 0; n < 4; ++n) oacc[m][n] = fz;
    float m_run[2] = {-1e30f, -1e30f};
    float l_run[2] = {0.f, 0.f};

    char* Klb = (char*)Klds;
    char* Vtb = (char*)Vtlds;
    char* Pb = (char*)Plds + w * 4096;

    const int skey = tid & 63, sseg = tid >> 6;        // K staging
    const int vkey = (tid & 31) * 2, vd0 = (tid >> 5) * 8; // V staging

#pragma unroll 1
    for (int kt = 0; kt < 32; ++kt) {
        const int kb0 = kt * 64;
        __syncthreads();
        {   // stage K [key][d]
            const u16* gk = &kb[hbase + (size_t)(kb0 + skey) * 256 + sseg * 16];
            uint4 d0 = *(const uint4*)gk;
            uint4 d1 = *(const uint4*)(gk + 8);
            const u32 sw = (u32)((skey & 7) << 4);
            const u32 ba = (u32)(skey * 128 + sseg * 32);
            *(uint4*)(Klb + ((ba) ^ sw)) = d0;
            *(uint4*)(Klb + ((ba + 16) ^ sw)) = d1;
        }
        {   // stage V transposed [d][key]
            const u16* gv = &vb[hbase + (size_t)(kb0 + vkey) * 256 + vd0];
            union { uint4 v; u16 h[8]; } r0, r1;
            r0.v = *(const uint4*)gv;
            r1.v = *(const uint4*)(gv + 256);
#pragma unroll
            for (int i = 0; i < 8; ++i) {
                const int d = vd0 + i;
                const u32 addr = (u32)(d * 128 + vkey * 2) ^ (u32)((d & 7) << 4);
                *(u32*)(Vtb + addr) = (u32)r0.h[i] | ((u32)r1.h[i] << 16);
            }
        }
        __syncthreads();

        // QK^T (swapped): sc[km][qn] holds S^T[key][q]
        f32x4 sc[4][2];
#pragma unroll
        for (int km = 0; km < 4; ++km)
#pragma unroll
            for (int qn = 0; qn < 2; ++qn) sc[km][qn] = fz;
#pragma unroll
        for (int c = 0; c < 2; ++c)
#pragma unroll
            for (int km = 0; km < 4; ++km) {
                const int key = km * 16 + lo;
                const u32 addr = (u32)(key * 128 + c * 64 + g * 16) ^ (u32)((key & 7) << 4);
                const short8 kf = *(const short8*)(Klb + addr);
#pragma unroll
                for (int qn = 0; qn < 2; ++qn)
                    sc[km][qn] = __builtin_amdgcn_mfma_f32_16x16x32_bf16(kf, qf[qn][c], sc[km][qn], 0, 0, 0);
            }

        // online softmax per q-block
        float alpha[2];
#pragma unroll
        for (int qn = 0; qn < 2; ++qn) {
            float mt = -1e30f;
#pragma unroll
            for (int km = 0; km < 4; ++km)
#pragma unroll
                for (int r = 0; r < 4; ++r) mt = fmaxf(mt, sc[km][qn][r]);
            mt = fmaxf(mt, __shfl_xor(mt, 16));
            mt = fmaxf(mt, __shfl_xor(mt, 32));
            const float mnew = fmaxf(m_run[qn], mt);
            alpha[qn] = __builtin_amdgcn_exp2f((m_run[qn] - mnew) * LOG2E);
            float ls = 0.f;
#pragma unroll
            for (int km = 0; km < 4; ++km)
#pragma unroll
                for (int r = 0; r < 4; ++r) {
                    const float p = __builtin_amdgcn_exp2f((sc[km][qn][r] - mnew) * LOG2E);
                    sc[km][qn][r] = p;
                    ls += p;
                }
            ls += __shfl_xor(ls, 16);
            ls += __shfl_xor(ls, 32);
            l_run[qn] = l_run[qn] * alpha[qn] + ls;
            m_run[qn] = mnew;
        }

        // P^T -> P_lds ([q][key], swizzled)
#pragma unroll
        for (int qn = 0; qn < 2; ++qn) {
            const int q = qn * 16 + lo;
            const u32 sw = (u32)((q & 7) << 4);
#pragma unroll
            for (int km = 0; km < 4; ++km) {
                uint2 val;
                val.x = (u32)f2bf(sc[km][qn][0]) | ((u32)f2bf(sc[km][qn][1]) << 16);
                val.y = (u32)f2bf(sc[km][qn][2]) | ((u32)f2bf(sc[km][qn][3]) << 16);
                const u32 addr = (u32)(q * 128 + km * 32 + g * 8) ^ sw;
                *(uint2*)(Pb + addr) = val;
            }
        }

        // rescale O acc by alpha (broadcast per acc row)
#pragma unroll
        for (int m = 0; m < 2; ++m)
#pragma unroll
            for (int r = 0; r < 4; ++r) {
                const float a = __shfl(alpha[m], (lane & 48) | (g * 4 + r));
#pragma unroll
                for (int n = 0; n < 4; ++n) oacc[m][n][r] *= a;
            }

        // PV
#pragma unroll
        for (int c = 0; c < 2; ++c) {
            short8 pf[2];
#pragma unroll
            for (int m = 0; m < 2; ++m) {
                const int q = m * 16 + lo;
                const u32 addr = (u32)(q * 128 + c * 64 + g * 16) ^ (u32)((q & 7) << 4);
                pf[m] = *(const short8*)(Pb + addr);
            }
#pragma unroll
            for (int n = 0; n < 4; ++n) {
                const int d = n * 16 + lo;
                const u32 addr = (u32)(d * 128 + c * 64 + g * 16) ^ (u32)((d & 7) << 4);
                const short8 vf = *(const short8*)(Vtb + addr);
#pragma unroll
                for (int m = 0; m < 2; ++m)
                    oacc[m][n] = __builtin_amdgcn_mfma_f32_16x16x32_bf16(pf[m], vf, oacc[m][n], 0, 0, 0);
            }
        }
    }

    // finalize: O = q + oacc / l_run
#pragma unroll
    for (int m = 0; m < 2; ++m)
#pragma unroll
        for (int r = 0; r < 4; ++r) {
            const float li = 1.0f / __shfl(l_run[m], (lane & 48) | (g * 4 + r));
            const size_t row = (size_t)(q0 + w * 32 + m * 16 + g * 4 + r);
#pragma unroll
            for (int n = 0; n < 4; ++n) {
                const int d = n * 16 + lo;
                const size_t idx = hbase + row * 256 + d;
                Obuf[idx] = oacc[m][n][r] * li + bf2f(qb[idx]);
            }
        }
}

// ---------------------------------------------------------------- LayerNorm (wave per 256-row)
// May run IN-PLACE (of == in): each lane reads its own float4 before writing it. No restrict.
template<bool WB>
__global__ __launch_bounds__(256)
void ln_kernel(const float* in, const float* __restrict__ gam,
               const float* __restrict__ bet, float* of,
               u16* __restrict__ ob) {
    const int w = threadIdx.x >> 6, lane = threadIdx.x & 63;
    const size_t row = (size_t)blockIdx.x * 4 + w;
    const float4 v = ((const float4*)(in + row * 256))[lane];
    float s = v.x + v.y + v.z + v.w;
    float q = v.x * v.x + v.y * v.y + v.z * v.z + v.w * v.w;
#pragma unroll
    for (int m = 1; m <= 32; m <<= 1) {
        s += __shfl_xor(s, m);
        q += __shfl_xor(q, m);
    }
    const float mu = s * (1.f / 256.f);
    const float var = q * (1.f / 256.f) - mu * mu;
    const float rstd = rsqrtf(var + 1e-5f);
    const float4 gv = ((const float4*)gam)[lane];
    const float4 bv = ((const float4*)bet)[lane];
    float4 y;
    y.x = (v.x - mu) * rstd * gv.x + bv.x;
    y.y = (v.y - mu) * rstd * gv.y + bv.y;
    y.z = (v.z - mu) * rstd * gv.z + bv.z;
    y.w = (v.w - mu) * rstd * gv.w + bv.w;
    ((float4*)(of + row * 256))[lane] = y;
    if (WB) {
        uint2 pk;
        pk.x = (u32)f2bf(y.x) | ((u32)f2bf(y.y) << 16);
        pk.y = (u32)f2bf(y.z) | ((u32)f2bf(y.w) << 16);
        *(uint2*)(ob + row * 256 + lane * 4) = pk;
    }
}

// ----------------------------------------------------------------------------------------------
// Workspace: Qc 8MB | Kc 8MB | qb 8MB | kbuf 8MB | vbuf 8MB | WT 0.5MB | bks — total ~40.6MB.
// Xb aliases Qc (dead after q-projection). Attention out / LN0 / MLP / LN1 chain in-place on d_out.
extern "C" void kernel_launch(void* const* d_in, const int* in_sizes, int n_in,
                              void* d_out, int out_size, void* d_ws, size_t ws_size,
                              hipStream_t stream) {
    const float* Q  = (const float*)d_in[0];
    const float* K  = (const float*)d_in[1];
    const float* Wq = (const float*)d_in[2];
    const float* bq = (const float*)d_in[3];
    const float* Wk = (const float*)d_in[4];
    const float* bk = (const float*)d_in[5];
    const float* Wv = (const float*)d_in[6];
    const float* bv = (const float*)d_in[7];
    const float* Wo = (const float*)d_in[8];
    const float* bo = (const float*)d_in[9];
    const float* g0 = (const float*)d_in[10];
    const float* be0 = (const float*)d_in[11];
    const float* g1 = (const float*)d_in[12];
    const float* be1 = (const float*)d_in[13];
    float* out = (float*)d_out;

    const size_t NE = (size_t)8 * 2048 * 256;  // 4,194,304
    char* ws = (char*)d_ws;
    size_t off = 0;
    auto alloc = [&](size_t bytes) { char* p = ws + off; off += (bytes + 255) & ~(size_t)255; return p; };
    u16* Qc   = (u16*)alloc(NE * 2);
    u16* Kc   = (u16*)alloc(NE * 2);
    u16* qb   = (u16*)alloc(NE * 2);
    u16* kbuf = (u16*)alloc(NE * 2);
    u16* vbuf = (u16*)alloc(NE * 2);
    u16* WT   = (u16*)alloc(4 * 65536 * 2);
    float* bks = (float*)alloc(256 * 4);
    u16* Xb   = Qc;          // alias: Qc dead after q-projection GEMM, Xb written by LN0 later
    float* Obuf = out;       // attention output lives in d_out; LN0/MLP/LN1 run in-place on it

    cvt_kernel<<<2048, 256, 0, stream>>>(Q, Qc);
    cvt_kernel<<<2048, 256, 0, stream>>>(K, Kc);
    wt_kernel<<<dim3(256, 4), 256, 0, stream>>>(Wq, Wk, Wv, Wo, bk, WT, bks);

    dim3 gg(128, 2);
    gemm_kernel<0><<<gg, 256, 0, stream>>>(Qc, WT,             bq,  nullptr, (void*)qb);
    gemm_kernel<0><<<gg, 256, 0, stream>>>(Kc, WT + 65536,     bks, nullptr, (void*)kbuf);
    gemm_kernel<0><<<gg, 256, 0, stream>>>(Kc, WT + 2 * 65536, bv,  nullptr, (void*)vbuf);

    attn_kernel<<<dim3(16, 4, 8), 256, 0, stream>>>(qb, kbuf, vbuf, Obuf);

    ln_kernel<true><<<4096, 256, 0, stream>>>(Obuf, g0, be0, Obuf, Xb);       // in-place LN0
    gemm_kernel<1><<<gg, 256, 0, stream>>>(Xb, WT + 3 * 65536, bo, Obuf, (void*)Obuf); // in-place MLP
    ln_kernel<false><<<4096, 256, 0, stream>>>(Obuf, g1, be1, out, nullptr);  // in-place LN1
}

// Round 4
// 157.203 us; speedup vs baseline: 1.2080x; 1.2080x over previous
//
#include <hip/hip_runtime.h>
#include <hip/hip_bf16.h>
#include <stdint.h>

typedef uint16_t u16;
typedef uint32_t u32;
typedef __attribute__((ext_vector_type(8))) short short8;   // 8 x bf16 (MFMA A/B frag)
typedef __attribute__((ext_vector_type(4))) float f32x4;    // MFMA C/D frag

#define LOG2E 1.44269504088896340736f

__device__ __forceinline__ u16 f2bf(float f) {
    u32 u = __builtin_bit_cast(u32, f);
    return (u16)((u + 0x7fffu + ((u >> 16) & 1u)) >> 16);   // RNE
}
__device__ __forceinline__ float bf2f(u16 h) {
    u32 u = ((u32)h) << 16;
    return __builtin_bit_cast(float, u);
}

// ------------------------------------------- convert f32 -> bf16, Q and K in one launch
__global__ __launch_bounds__(256)
void cvt2_kernel(const float* __restrict__ Q, const float* __restrict__ K,
                 u16* __restrict__ Qc, u16* __restrict__ Kc) {
    const int bid = blockIdx.x;
    const float* src = (bid < 2048) ? Q : K;
    u16* dst = (bid < 2048) ? Qc : Kc;
    const size_t i = ((size_t)(bid & 2047) * 256 + threadIdx.x) * 8;
    float4 a = *(const float4*)(src + i);
    float4 b = *(const float4*)(src + i + 4);
    uint4 o;
    o.x = (u32)f2bf(a.x) | ((u32)f2bf(a.y) << 16);
    o.y = (u32)f2bf(a.z) | ((u32)f2bf(a.w) << 16);
    o.z = (u32)f2bf(b.x) | ((u32)f2bf(b.y) << 16);
    o.w = (u32)f2bf(b.z) | ((u32)f2bf(b.w) << 16);
    *(uint4*)(dst + i) = o;
}

// ------------------- weights: transpose + bf16 (+ fold 0.125*log2(e) into Wk,bk -> log2-domain scores)
__global__ void wt_kernel(const float* __restrict__ Wq, const float* __restrict__ Wk,
                          const float* __restrict__ Wv, const float* __restrict__ Wo,
                          const float* __restrict__ bk, u16* __restrict__ WT,
                          float* __restrict__ bks) {
    const int wsel = blockIdx.y, k = blockIdx.x, n = threadIdx.x;
    const float* W = (wsel == 0) ? Wq : (wsel == 1) ? Wk : (wsel == 2) ? Wv : Wo;
    const float scale = (wsel == 1) ? (0.125f * LOG2E) : 1.0f;
    WT[(size_t)wsel * 65536 + (size_t)n * 256 + k] = f2bf(W[(size_t)k * 256 + n] * scale);
    if (wsel == 1 && k == 0) bks[n] = bk[n] * (0.125f * LOG2E);
}

// ---------------------------------------------------------------- GEMM: C = A[M,256] @ W[256,256]
// BT is pre-transposed weights BT[n][k]. EPI=0: out bf16 = acc+bias. EPI=1: out f32 = resid + relu(acc+bias).
// EPI=1 may run IN-PLACE (outp == resid): per-index read-then-write by the same thread, no restrict.
// 128x128 tile, 4 waves (64x64 each), BK=64, XOR-swizzled LDS (conflict-free ds_read_b128).
template<int EPI>
__global__ __launch_bounds__(256)
void gemm_kernel(const u16* __restrict__ A, const u16* __restrict__ BT,
                 const float* __restrict__ bias, const float* resid,
                 void* outp) {
    __shared__ u16 As[128 * 64];
    __shared__ u16 Bs[128 * 64];
    const int tid = threadIdx.x;
    const int w = tid >> 6, lane = tid & 63;
    const int g = lane >> 4, lo = lane & 15;
    const int rowB = blockIdx.x * 128;
    const int colB = blockIdx.y * 128;
    const int wr = (w >> 1) * 64, wc = (w & 1) * 64;

    const f32x4 fz = {0.f, 0.f, 0.f, 0.f};
    f32x4 acc[4][4];
#pragma unroll
    for (int m = 0; m < 4; ++m)
#pragma unroll
        for (int n = 0; n < 4; ++n) acc[m][n] = fz;

    const int srow = tid & 127;   // staging: row in tile
    const int shalf = tid >> 7;   // 0/1: which 32-elem (64-byte) half of the 64-wide K slab

#pragma unroll 1
    for (int kt = 0; kt < 4; ++kt) {
        const int k0 = kt * 64;
        __syncthreads();
        {
            const u16* ga = A + (size_t)(rowB + srow) * 256 + k0 + shalf * 32;
            uint4 a0 = *(const uint4*)ga;
            uint4 a1 = *(const uint4*)(ga + 8);
            uint4 a2 = *(const uint4*)(ga + 16);
            uint4 a3 = *(const uint4*)(ga + 24);
            const u16* gb = BT + (size_t)(colB + srow) * 256 + k0 + shalf * 32;
            uint4 b0 = *(const uint4*)gb;
            uint4 b1 = *(const uint4*)(gb + 8);
            uint4 b2 = *(const uint4*)(gb + 16);
            uint4 b3 = *(const uint4*)(gb + 24);
            const u32 sw = (u32)((srow & 7) << 4);
            const u32 ba = (u32)(srow * 128 + shalf * 64);
            *(uint4*)((char*)As + ((ba) ^ sw))      = a0;
            *(uint4*)((char*)As + ((ba + 16) ^ sw)) = a1;
            *(uint4*)((char*)As + ((ba + 32) ^ sw)) = a2;
            *(uint4*)((char*)As + ((ba + 48) ^ sw)) = a3;
            *(uint4*)((char*)Bs + ((ba) ^ sw))      = b0;
            *(uint4*)((char*)Bs + ((ba + 16) ^ sw)) = b1;
            *(uint4*)((char*)Bs + ((ba + 32) ^ sw)) = b2;
            *(uint4*)((char*)Bs + ((ba + 48) ^ sw)) = b3;
        }
        __syncthreads();
#pragma unroll
        for (int c = 0; c < 2; ++c) {
            short8 af[4], bfr[4];
#pragma unroll
            for (int m = 0; m < 4; ++m) {
                const int row = wr + m * 16 + lo;
                const u32 addr = (u32)(row * 128 + c * 64 + g * 16) ^ (u32)((row & 7) << 4);
                af[m] = *(const short8*)((char*)As + addr);
            }
#pragma unroll
            for (int n = 0; n < 4; ++n) {
                const int row = wc + n * 16 + lo;
                const u32 addr = (u32)(row * 128 + c * 64 + g * 16) ^ (u32)((row & 7) << 4);
                bfr[n] = *(const short8*)((char*)Bs + addr);
            }
#pragma unroll
            for (int m = 0; m < 4; ++m)
#pragma unroll
                for (int n = 0; n < 4; ++n)
                    acc[m][n] = __builtin_amdgcn_mfma_f32_16x16x32_bf16(af[m], bfr[n], acc[m][n], 0, 0, 0);
        }
    }

    float bv[4];
#pragma unroll
    for (int n = 0; n < 4; ++n) bv[n] = bias[colB + wc + n * 16 + lo];

    if (EPI == 0) {
        u16* out = (u16*)outp;
#pragma unroll
        for (int m = 0; m < 4; ++m)
#pragma unroll
            for (int r = 0; r < 4; ++r) {
                const size_t row = (size_t)(rowB + wr + m * 16 + g * 4 + r);
#pragma unroll
                for (int n = 0; n < 4; ++n)
                    out[row * 256 + colB + wc + n * 16 + lo] = f2bf(acc[m][n][r] + bv[n]);
            }
    } else {
        float* out = (float*)outp;
#pragma unroll
        for (int m = 0; m < 4; ++m)
#pragma unroll
            for (int r = 0; r < 4; ++r) {
                const size_t row = (size_t)(rowB + wr + m * 16 + g * 4 + r);
#pragma unroll
                for (int n = 0; n < 4; ++n) {
                    const size_t idx = row * 256 + colB + wc + n * 16 + lo;
                    out[idx] = resid[idx] + fmaxf(acc[m][n][r] + bv[n], 0.f);
                }
            }
    }
}

// ---------------------------------------------------------------- flash attention + q-residual
// grid (16 qtiles, H=4, B=8), 512 threads = 8 waves x 16 q-rows (128 q-rows/block).
// 16 waves/CU (2 blocks) vs 8 before. Swapped QK^T: mfma(K, Q) -> S^T; key-reduce = 2 shfl_xor.
// kb pre-scaled by 0.125*log2(e): softmax runs in log2 domain (exp2 without multiply).
// Defer-max (THR=11.5 log2-units ~ e^8): skip alpha/rescale when no row's max grew.
__global__ __launch_bounds__(512, 4)
void attn_kernel(const u16* __restrict__ qb, const u16* __restrict__ kb,
                 const u16* __restrict__ vb, float* __restrict__ Obuf) {
    __shared__ u16 Klds[64 * 64];     // [key][d], swizzled (8 KB)
    __shared__ u16 Vtlds[64 * 64];    // [d][key], swizzled (8 KB)
    __shared__ u16 Plds[8 * 16 * 64]; // per-wave [q16][key64], swizzled (16 KB)
    const int tid = threadIdx.x;
    const int w = tid >> 6, lane = tid & 63;
    const int g = lane >> 4, lo = lane & 15;
    const int q0 = blockIdx.x * 128;
    const int h = blockIdx.y, b = blockIdx.z;
    const size_t hbase = (size_t)b * 2048 * 256 + (size_t)h * 64;

    short8 qf[2];   // B-frags of Q for this wave's 16 q-rows (q = lo)
#pragma unroll
    for (int c = 0; c < 2; ++c) {
        const size_t row = (size_t)(q0 + w * 16 + lo);
        qf[c] = *(const short8*)&qb[hbase + row * 256 + c * 32 + g * 8];
    }

    const f32x4 fz = {0.f, 0.f, 0.f, 0.f};
    f32x4 oacc[4];
#pragma unroll
    for (int n = 0; n < 4; ++n) oacc[n] = fz;
    float m_run = -1e30f;   // per q = lo (log2 units)
    float l_run = 0.f;

    char* Klb = (char*)Klds;
    char* Vtb = (char*)Vtlds;
    char* Pb = (char*)Plds + w * 2048;

#pragma unroll 1
    for (int kt = 0; kt < 32; ++kt) {
        const int kb0 = kt * 64;
        __syncthreads();
        if (tid < 256) {   // waves 0-3: stage K [key][d]
            const int skey = tid & 63, sseg = tid >> 6;
            const u16* gk = &kb[hbase + (size_t)(kb0 + skey) * 256 + sseg * 16];
            uint4 d0 = *(const uint4*)gk;
            uint4 d1 = *(const uint4*)(gk + 8);
            const u32 sw = (u32)((skey & 7) << 4);
            const u32 ba = (u32)(skey * 128 + sseg * 32);
            *(uint4*)(Klb + ((ba) ^ sw)) = d0;
            *(uint4*)(Klb + ((ba + 16) ^ sw)) = d1;
        } else {           // waves 4-7: stage V transposed [d][key]
            const int t = tid - 256;
            const int vkey = (t & 31) * 2, vd0 = (t >> 5) * 8;
            const u16* gv = &vb[hbase + (size_t)(kb0 + vkey) * 256 + vd0];
            union { uint4 v; u16 hh[8]; } r0, r1;
            r0.v = *(const uint4*)gv;
            r1.v = *(const uint4*)(gv + 256);
#pragma unroll
            for (int i = 0; i < 8; ++i) {
                const int d = vd0 + i;
                const u32 addr = (u32)(d * 128 + vkey * 2) ^ (u32)((d & 7) << 4);
                *(u32*)(Vtb + addr) = (u32)r0.hh[i] | ((u32)r1.hh[i] << 16);
            }
        }
        __syncthreads();

        // QK^T (swapped): sc[km] holds S^T[key = km*16 + g*4 + r][q = lo] (log2 units)
        f32x4 sc[4];
#pragma unroll
        for (int km = 0; km < 4; ++km) sc[km] = fz;
#pragma unroll
        for (int c = 0; c < 2; ++c)
#pragma unroll
            for (int km = 0; km < 4; ++km) {
                const int key = km * 16 + lo;
                const u32 addr = (u32)(key * 128 + c * 64 + g * 16) ^ (u32)((key & 7) << 4);
                const short8 kf = *(const short8*)(Klb + addr);
                sc[km] = __builtin_amdgcn_mfma_f32_16x16x32_bf16(kf, qf[c], sc[km], 0, 0, 0);
            }

        // online softmax (per q = lo), deferred-max
        float mt = -1e30f;
#pragma unroll
        for (int km = 0; km < 4; ++km)
#pragma unroll
            for (int r = 0; r < 4; ++r) mt = fmaxf(mt, sc[km][r]);
        mt = fmaxf(mt, __shfl_xor(mt, 16));
        mt = fmaxf(mt, __shfl_xor(mt, 32));
        if (!__all(mt <= m_run + 11.5f)) {
            const float mnew = fmaxf(m_run, mt);
            const float alpha = __builtin_amdgcn_exp2f(m_run - mnew);
            l_run *= alpha;
#pragma unroll
            for (int r = 0; r < 4; ++r) {
                const float a = __shfl(alpha, (lane & 48) | (g * 4 + r));
#pragma unroll
                for (int n = 0; n < 4; ++n) oacc[n][r] *= a;
            }
            m_run = mnew;
        }
        float ls = 0.f;
#pragma unroll
        for (int km = 0; km < 4; ++km)
#pragma unroll
            for (int r = 0; r < 4; ++r) {
                const float p = __builtin_amdgcn_exp2f(sc[km][r] - m_run);
                sc[km][r] = p;
                ls += p;
            }
        ls += __shfl_xor(ls, 16);
        ls += __shfl_xor(ls, 32);
        l_run += ls;

        // P^T -> P_lds ([q][key], swizzled); thread's keys = km*16 + g*4 + {0..3}
        {
            const u32 sw = (u32)((lo & 7) << 4);
#pragma unroll
            for (int km = 0; km < 4; ++km) {
                uint2 val;
                val.x = (u32)f2bf(sc[km][0]) | ((u32)f2bf(sc[km][1]) << 16);
                val.y = (u32)f2bf(sc[km][2]) | ((u32)f2bf(sc[km][3]) << 16);
                const u32 addr = (u32)(lo * 128 + km * 32 + g * 8) ^ sw;
                *(uint2*)(Pb + addr) = val;
            }
        }

        // PV: oacc[n] += P[16 x 64] @ V[64 x d16]
#pragma unroll
        for (int c = 0; c < 2; ++c) {
            const u32 paddr = (u32)(lo * 128 + c * 64 + g * 16) ^ (u32)((lo & 7) << 4);
            const short8 pf = *(const short8*)(Pb + paddr);
#pragma unroll
            for (int n = 0; n < 4; ++n) {
                const int d = n * 16 + lo;
                const u32 addr = (u32)(d * 128 + c * 64 + g * 16) ^ (u32)((d & 7) << 4);
                const short8 vf = *(const short8*)(Vtb + addr);
                oacc[n] = __builtin_amdgcn_mfma_f32_16x16x32_bf16(pf, vf, oacc[n], 0, 0, 0);
            }
        }
    }

    // finalize: O = q + oacc / l_run
#pragma unroll
    for (int r = 0; r < 4; ++r) {
        const float li = 1.0f / __shfl(l_run, (lane & 48) | (g * 4 + r));
        const size_t row = (size_t)(q0 + w * 16 + g * 4 + r);
#pragma unroll
        for (int n = 0; n < 4; ++n) {
            const int d = n * 16 + lo;
            const size_t idx = hbase + row * 256 + d;
            Obuf[idx] = oacc[n][r] * li + bf2f(qb[idx]);
        }
    }
}

// ---------------------------------------------------------------- LayerNorm (wave per 256-row)
// May run IN-PLACE (of == in): each lane reads its own float4 before writing it. No restrict.
template<bool WB>
__global__ __launch_bounds__(256)
void ln_kernel(const float* in, const float* __restrict__ gam,
               const float* __restrict__ bet, float* of,
               u16* __restrict__ ob) {
    const int w = threadIdx.x >> 6, lane = threadIdx.x & 63;
    const size_t row = (size_t)blockIdx.x * 4 + w;
    const float4 v = ((const float4*)(in + row * 256))[lane];
    float s = v.x + v.y + v.z + v.w;
    float q = v.x * v.x + v.y * v.y + v.z * v.z + v.w * v.w;
#pragma unroll
    for (int m = 1; m <= 32; m <<= 1) {
        s += __shfl_xor(s, m);
        q += __shfl_xor(q, m);
    }
    const float mu = s * (1.f / 256.f);
    const float var = q * (1.f / 256.f) - mu * mu;
    const float rstd = rsqrtf(var + 1e-5f);
    const float4 gv = ((const float4*)gam)[lane];
    const float4 bv = ((const float4*)bet)[lane];
    float4 y;
    y.x = (v.x - mu) * rstd * gv.x + bv.x;
    y.y = (v.y - mu) * rstd * gv.y + bv.y;
    y.z = (v.z - mu) * rstd * gv.z + bv.z;
    y.w = (v.w - mu) * rstd * gv.w + bv.w;
    ((float4*)(of + row * 256))[lane] = y;
    if (WB) {
        uint2 pk;
        pk.x = (u32)f2bf(y.x) | ((u32)f2bf(y.y) << 16);
        pk.y = (u32)f2bf(y.z) | ((u32)f2bf(y.w) << 16);
        *(uint2*)(ob + row * 256 + lane * 4) = pk;
    }
}

// ----------------------------------------------------------------------------------------------
// Workspace: Qc 8MB | Kc 8MB | qb 8MB | kbuf 8MB | vbuf 8MB | WT 0.5MB | bks — total ~40.6MB.
// Xb aliases Qc (dead after q-projection). Attention out / LN0 / MLP / LN1 chain in-place on d_out.
extern "C" void kernel_launch(void* const* d_in, const int* in_sizes, int n_in,
                              void* d_out, int out_size, void* d_ws, size_t ws_size,
                              hipStream_t stream) {
    const float* Q  = (const float*)d_in[0];
    const float* K  = (const float*)d_in[1];
    const float* Wq = (const float*)d_in[2];
    const float* bq = (const float*)d_in[3];
    const float* Wk = (const float*)d_in[4];
    const float* bk = (const float*)d_in[5];
    const float* Wv = (const float*)d_in[6];
    const float* bv = (const float*)d_in[7];
    const float* Wo = (const float*)d_in[8];
    const float* bo = (const float*)d_in[9];
    const float* g0 = (const float*)d_in[10];
    const float* be0 = (const float*)d_in[11];
    const float* g1 = (const float*)d_in[12];
    const float* be1 = (const float*)d_in[13];
    float* out = (float*)d_out;

    const size_t NE = (size_t)8 * 2048 * 256;  // 4,194,304
    char* ws = (char*)d_ws;
    size_t off = 0;
    auto alloc = [&](size_t bytes) { char* p = ws + off; off += (bytes + 255) & ~(size_t)255; return p; };
    u16* Qc   = (u16*)alloc(NE * 2);
    u16* Kc   = (u16*)alloc(NE * 2);
    u16* qb   = (u16*)alloc(NE * 2);
    u16* kbuf = (u16*)alloc(NE * 2);
    u16* vbuf = (u16*)alloc(NE * 2);
    u16* WT   = (u16*)alloc(4 * 65536 * 2);
    float* bks = (float*)alloc(256 * 4);
    u16* Xb   = Qc;          // alias: Qc dead after q-projection GEMM, Xb written by LN0 later
    float* Obuf = out;       // attention output lives in d_out; LN0/MLP/LN1 run in-place on it

    cvt2_kernel<<<4096, 256, 0, stream>>>(Q, K, Qc, Kc);
    wt_kernel<<<dim3(256, 4), 256, 0, stream>>>(Wq, Wk, Wv, Wo, bk, WT, bks);

    dim3 gg(128, 2);
    gemm_kernel<0><<<gg, 256, 0, stream>>>(Qc, WT,             bq,  nullptr, (void*)qb);
    gemm_kernel<0><<<gg, 256, 0, stream>>>(Kc, WT + 65536,     bks, nullptr, (void*)kbuf);
    gemm_kernel<0><<<gg, 256, 0, stream>>>(Kc, WT + 2 * 65536, bv,  nullptr, (void*)vbuf);

    attn_kernel<<<dim3(16, 4, 8), 512, 0, stream>>>(qb, kbuf, vbuf, Obuf);

    ln_kernel<true><<<4096, 256, 0, stream>>>(Obuf, g0, be0, Obuf, Xb);       // in-place LN0
    gemm_kernel<1><<<gg, 256, 0, stream>>>(Xb, WT + 3 * 65536, bo, Obuf, (void*)Obuf); // in-place MLP
    ln_kernel<false><<<4096, 256, 0, stream>>>(Obuf, g1, be1, out, nullptr);  // in-place LN1
}

// Round 5
// 134.401 us; speedup vs baseline: 1.4129x; 1.1697x over previous
//
#include <hip/hip_runtime.h>
#include <hip/hip_bf16.h>
#include <stdint.h>

typedef uint16_t u16;
typedef uint32_t u32;
typedef __attribute__((ext_vector_type(8))) short short8;   // 8 x bf16 (MFMA A/B frag)
typedef __attribute__((ext_vector_type(4))) float f32x4;    // MFMA C/D frag

#define LOG2E 1.44269504088896340736f

__device__ __forceinline__ u16 f2bf(float f) {
    u32 u = __builtin_bit_cast(u32, f);
    return (u16)((u + 0x7fffu + ((u >> 16) & 1u)) >> 16);   // RNE
}
__device__ __forceinline__ float bf2f(u16 h) {
    u32 u = ((u32)h) << 16;
    return __builtin_bit_cast(float, u);
}

// ------------------------------------------- convert f32 -> bf16, Q and K in one launch
__global__ __launch_bounds__(256)
void cvt2_kernel(const float* __restrict__ Q, const float* __restrict__ K,
                 u16* __restrict__ Qc, u16* __restrict__ Kc) {
    const int bid = blockIdx.x;
    const float* src = (bid < 2048) ? Q : K;
    u16* dst = (bid < 2048) ? Qc : Kc;
    const size_t i = ((size_t)(bid & 2047) * 256 + threadIdx.x) * 8;
    float4 a = *(const float4*)(src + i);
    float4 b = *(const float4*)(src + i + 4);
    uint4 o;
    o.x = (u32)f2bf(a.x) | ((u32)f2bf(a.y) << 16);
    o.y = (u32)f2bf(a.z) | ((u32)f2bf(a.w) << 16);
    o.z = (u32)f2bf(b.x) | ((u32)f2bf(b.y) << 16);
    o.w = (u32)f2bf(b.z) | ((u32)f2bf(b.w) << 16);
    *(uint4*)(dst + i) = o;
}

// ------------------- weights: transpose + bf16 (+ fold 0.125*log2(e) into Wk,bk -> log2-domain scores)
__global__ void wt_kernel(const float* __restrict__ Wq, const float* __restrict__ Wk,
                          const float* __restrict__ Wv, const float* __restrict__ Wo,
                          const float* __restrict__ bk, u16* __restrict__ WT,
                          float* __restrict__ bks) {
    const int wsel = blockIdx.y, k = blockIdx.x, n = threadIdx.x;
    const float* W = (wsel == 0) ? Wq : (wsel == 1) ? Wk : (wsel == 2) ? Wv : Wo;
    const float scale = (wsel == 1) ? (0.125f * LOG2E) : 1.0f;
    WT[(size_t)wsel * 65536 + (size_t)n * 256 + k] = f2bf(W[(size_t)k * 256 + n] * scale);
    if (wsel == 1 && k == 0) bks[n] = bk[n] * (0.125f * LOG2E);
}

// ---------------------------------------------------------------- GEMM body: C = A[M,256] @ W[256,256]
// BT is pre-transposed weights BT[n][k]. EPI=0: out bf16 = acc+bias. EPI=1: out f32 = resid + relu(acc+bias).
// EPI=1 may run IN-PLACE (outp == resid). 128x128 tile, 4 waves, BK=64, XOR-swizzled LDS.
template<int EPI>
__device__ __forceinline__ void gemm_body(const u16* __restrict__ A, const u16* __restrict__ BT,
                                          const float* __restrict__ bias, const float* resid,
                                          void* outp) {
    __shared__ u16 As[128 * 64];
    __shared__ u16 Bs[128 * 64];
    const int tid = threadIdx.x;
    const int w = tid >> 6, lane = tid & 63;
    const int g = lane >> 4, lo = lane & 15;
    const int rowB = blockIdx.x * 128;
    const int colB = blockIdx.y * 128;
    const int wr = (w >> 1) * 64, wc = (w & 1) * 64;

    const f32x4 fz = {0.f, 0.f, 0.f, 0.f};
    f32x4 acc[4][4];
#pragma unroll
    for (int m = 0; m < 4; ++m)
#pragma unroll
        for (int n = 0; n < 4; ++n) acc[m][n] = fz;

    const int srow = tid & 127;   // staging: row in tile
    const int shalf = tid >> 7;   // 0/1: which 32-elem (64-byte) half of the 64-wide K slab

#pragma unroll 1
    for (int kt = 0; kt < 4; ++kt) {
        const int k0 = kt * 64;
        __syncthreads();
        {
            const u16* ga = A + (size_t)(rowB + srow) * 256 + k0 + shalf * 32;
            uint4 a0 = *(const uint4*)ga;
            uint4 a1 = *(const uint4*)(ga + 8);
            uint4 a2 = *(const uint4*)(ga + 16);
            uint4 a3 = *(const uint4*)(ga + 24);
            const u16* gb = BT + (size_t)(colB + srow) * 256 + k0 + shalf * 32;
            uint4 b0 = *(const uint4*)gb;
            uint4 b1 = *(const uint4*)(gb + 8);
            uint4 b2 = *(const uint4*)(gb + 16);
            uint4 b3 = *(const uint4*)(gb + 24);
            const u32 sw = (u32)((srow & 7) << 4);
            const u32 ba = (u32)(srow * 128 + shalf * 64);
            *(uint4*)((char*)As + ((ba) ^ sw))      = a0;
            *(uint4*)((char*)As + ((ba + 16) ^ sw)) = a1;
            *(uint4*)((char*)As + ((ba + 32) ^ sw)) = a2;
            *(uint4*)((char*)As + ((ba + 48) ^ sw)) = a3;
            *(uint4*)((char*)Bs + ((ba) ^ sw))      = b0;
            *(uint4*)((char*)Bs + ((ba + 16) ^ sw)) = b1;
            *(uint4*)((char*)Bs + ((ba + 32) ^ sw)) = b2;
            *(uint4*)((char*)Bs + ((ba + 48) ^ sw)) = b3;
        }
        __syncthreads();
#pragma unroll
        for (int c = 0; c < 2; ++c) {
            short8 af[4], bfr[4];
#pragma unroll
            for (int m = 0; m < 4; ++m) {
                const int row = wr + m * 16 + lo;
                const u32 addr = (u32)(row * 128 + c * 64 + g * 16) ^ (u32)((row & 7) << 4);
                af[m] = *(const short8*)((char*)As + addr);
            }
#pragma unroll
            for (int n = 0; n < 4; ++n) {
                const int row = wc + n * 16 + lo;
                const u32 addr = (u32)(row * 128 + c * 64 + g * 16) ^ (u32)((row & 7) << 4);
                bfr[n] = *(const short8*)((char*)Bs + addr);
            }
#pragma unroll
            for (int m = 0; m < 4; ++m)
#pragma unroll
                for (int n = 0; n < 4; ++n)
                    acc[m][n] = __builtin_amdgcn_mfma_f32_16x16x32_bf16(af[m], bfr[n], acc[m][n], 0, 0, 0);
        }
    }

    float bv[4];
#pragma unroll
    for (int n = 0; n < 4; ++n) bv[n] = bias[colB + wc + n * 16 + lo];

    if (EPI == 0) {
        u16* out = (u16*)outp;
#pragma unroll
        for (int m = 0; m < 4; ++m)
#pragma unroll
            for (int r = 0; r < 4; ++r) {
                const size_t row = (size_t)(rowB + wr + m * 16 + g * 4 + r);
#pragma unroll
                for (int n = 0; n < 4; ++n)
                    out[row * 256 + colB + wc + n * 16 + lo] = f2bf(acc[m][n][r] + bv[n]);
            }
    } else {
        float* out = (float*)outp;
#pragma unroll
        for (int m = 0; m < 4; ++m)
#pragma unroll
            for (int r = 0; r < 4; ++r) {
                const size_t row = (size_t)(rowB + wr + m * 16 + g * 4 + r);
#pragma unroll
                for (int n = 0; n < 4; ++n) {
                    const size_t idx = row * 256 + colB + wc + n * 16 + lo;
                    out[idx] = resid[idx] + fmaxf(acc[m][n][r] + bv[n], 0.f);
                }
            }
    }
}

// Merged q/k/v projections: blockIdx.z selects which (3 blocks/CU instead of 3x 1 block/CU).
__global__ __launch_bounds__(256)
void proj_kernel(const u16* __restrict__ Qc, const u16* __restrict__ Kc,
                 const u16* __restrict__ WT, const float* __restrict__ bq,
                 const float* __restrict__ bks, const float* __restrict__ bvv,
                 u16* __restrict__ qb, u16* __restrict__ kbuf, u16* __restrict__ vbuf) {
    const int z = blockIdx.z;
    const u16* A = (z == 0) ? Qc : Kc;
    const u16* BT = WT + z * 65536;
    const float* bias = (z == 0) ? bq : (z == 1) ? bks : bvv;
    u16* out = (z == 0) ? qb : (z == 1) ? kbuf : vbuf;
    gemm_body<0>(A, BT, bias, nullptr, (void*)out);
}

// MLP: out f32 = resid + relu(A@Wo + bo), in-place on resid.
__global__ __launch_bounds__(256)
void mlp_kernel(const u16* __restrict__ A, const u16* __restrict__ BT,
                const float* __restrict__ bias, const float* resid, float* outp) {
    gemm_body<1>(A, BT, bias, resid, (void*)outp);
}

// ---------------------------------------------------------------- flash attention + q-residual
// grid (16 qtiles, H=4, B=8), 512 threads = 8 waves x 16 q-rows. Double-buffered K/V LDS:
// ONE barrier per K-tile; tile t+2's global loads issued at iter t (latency hidden under compute).
// Swapped QK^T: mfma(K, Q) -> S^T; key-reduce = 2 shfl_xor. kb pre-scaled by 0.125*log2(e)
// (log2-domain softmax). Defer-max THR=11.5 log2-units (~e^8).
__global__ __launch_bounds__(512, 4)
void attn_kernel(const u16* __restrict__ qb, const u16* __restrict__ kb,
                 const u16* __restrict__ vb, float* __restrict__ Obuf) {
    __shared__ u16 Klds[2 * 64 * 64];   // [buf][key][d], swizzled (16 KB)
    __shared__ u16 Vtlds[2 * 64 * 64];  // [buf][d][key], swizzled (16 KB)
    __shared__ u16 Plds[8 * 16 * 64];   // per-wave [q16][key64], swizzled (16 KB)
    const int tid = threadIdx.x;
    const int w = tid >> 6, lane = tid & 63;
    const int g = lane >> 4, lo = lane & 15;
    const int q0 = blockIdx.x * 128;
    const int h = blockIdx.y, b = blockIdx.z;
    const size_t hbase = (size_t)b * 2048 * 256 + (size_t)h * 64;

    short8 qf[2];   // B-frags of Q for this wave's 16 q-rows (q = lo)
#pragma unroll
    for (int c = 0; c < 2; ++c) {
        const size_t row = (size_t)(q0 + w * 16 + lo);
        qf[c] = *(const short8*)&qb[hbase + row * 256 + c * 32 + g * 8];
    }

    const f32x4 fz = {0.f, 0.f, 0.f, 0.f};
    f32x4 oacc[4];
#pragma unroll
    for (int n = 0; n < 4; ++n) oacc[n] = fz;
    float m_run = -1e30f;   // per q = lo (log2 units)
    float l_run = 0.f;

    char* Pb = (char*)Plds + w * 2048;

    // staging role: waves 0-3 stage K, waves 4-7 stage V-transpose
    const bool kRole = (tid < 256);
    const int skey = tid & 63, sseg = (tid >> 6) & 3;       // K role
    const int t4 = tid & 255;
    const int vkey = (t4 & 31) * 2, vd0 = (t4 >> 5) * 8;    // V role
    const u16* gbase;
    int goff2;
    if (kRole) { gbase = &kb[hbase + (size_t)skey * 256 + sseg * 16]; goff2 = 8; }
    else       { gbase = &vb[hbase + (size_t)vkey * 256 + vd0];       goff2 = 256; }

    uint4 s0, s1;   // staged registers (tile in flight)
    auto load_tile = [&](int kt) {
        const u16* p = gbase + (size_t)kt * 16384;
        s0 = *(const uint4*)p;
        s1 = *(const uint4*)(p + goff2);
    };
    auto write_tile = [&](int sel) {
        if (kRole) {
            char* Kb_ = (char*)Klds + sel * 8192;
            const u32 sw = (u32)((skey & 7) << 4);
            const u32 ba = (u32)(skey * 128 + sseg * 32);
            *(uint4*)(Kb_ + ((ba) ^ sw)) = s0;
            *(uint4*)(Kb_ + ((ba + 16) ^ sw)) = s1;
        } else {
            char* Vb_ = (char*)Vtlds + sel * 8192;
            union { uint4 v; u16 hh[8]; } a0, a1;
            a0.v = s0; a1.v = s1;
#pragma unroll
            for (int i = 0; i < 8; ++i) {
                const int d = vd0 + i;
                const u32 addr = (u32)(d * 128 + vkey * 2) ^ (u32)((d & 7) << 4);
                *(u32*)(Vb_ + addr) = (u32)a0.hh[i] | ((u32)a1.hh[i] << 16);
            }
        }
    };

    load_tile(0);
    write_tile(0);
    load_tile(1);
    __syncthreads();   // buf0 ready

#pragma unroll 1
    for (int kt = 0; kt < 32; ++kt) {
        const int cur = kt & 1;
        char* Klb = (char*)Klds + cur * 8192;
        char* Vtb = (char*)Vtlds + cur * 8192;

        // QK^T (swapped): sc[km] holds S^T[key = km*16 + g*4 + r][q = lo] (log2 units)
        f32x4 sc[4];
#pragma unroll
        for (int km = 0; km < 4; ++km) sc[km] = fz;
#pragma unroll
        for (int c = 0; c < 2; ++c)
#pragma unroll
            for (int km = 0; km < 4; ++km) {
                const int key = km * 16 + lo;
                const u32 addr = (u32)(key * 128 + c * 64 + g * 16) ^ (u32)((key & 7) << 4);
                const short8 kf = *(const short8*)(Klb + addr);
                sc[km] = __builtin_amdgcn_mfma_f32_16x16x32_bf16(kf, qf[c], sc[km], 0, 0, 0);
            }

        // online softmax (per q = lo), deferred-max
        float mt = -1e30f;
#pragma unroll
        for (int km = 0; km < 4; ++km)
#pragma unroll
            for (int r = 0; r < 4; ++r) mt = fmaxf(mt, sc[km][r]);
        mt = fmaxf(mt, __shfl_xor(mt, 16));
        mt = fmaxf(mt, __shfl_xor(mt, 32));
        if (!__all(mt <= m_run + 11.5f)) {
            const float mnew = fmaxf(m_run, mt);
            const float alpha = __builtin_amdgcn_exp2f(m_run - mnew);
            l_run *= alpha;
#pragma unroll
            for (int r = 0; r < 4; ++r) {
                const float a = __shfl(alpha, (lane & 48) | (g * 4 + r));
#pragma unroll
                for (int n = 0; n < 4; ++n) oacc[n][r] *= a;
            }
            m_run = mnew;
        }
        float ls = 0.f;
#pragma unroll
        for (int km = 0; km < 4; ++km)
#pragma unroll
            for (int r = 0; r < 4; ++r) {
                const float p = __builtin_amdgcn_exp2f(sc[km][r] - m_run);
                sc[km][r] = p;
                ls += p;
            }
        ls += __shfl_xor(ls, 16);
        ls += __shfl_xor(ls, 32);
        l_run += ls;

        // P^T -> P_lds ([q][key], swizzled); thread's keys = km*16 + g*4 + {0..3}
        {
            const u32 sw = (u32)((lo & 7) << 4);
#pragma unroll
            for (int km = 0; km < 4; ++km) {
                uint2 val;
                val.x = (u32)f2bf(sc[km][0]) | ((u32)f2bf(sc[km][1]) << 16);
                val.y = (u32)f2bf(sc[km][2]) | ((u32)f2bf(sc[km][3]) << 16);
                const u32 addr = (u32)(lo * 128 + km * 32 + g * 8) ^ sw;
                *(uint2*)(Pb + addr) = val;
            }
        }

        // PV: oacc[n] += P[16 x 64] @ V[64 x d16]   (same-wave P round trip, no barrier)
#pragma unroll
        for (int c = 0; c < 2; ++c) {
            const u32 paddr = (u32)(lo * 128 + c * 64 + g * 16) ^ (u32)((lo & 7) << 4);
            const short8 pf = *(const short8*)(Pb + paddr);
#pragma unroll
            for (int n = 0; n < 4; ++n) {
                const int d = n * 16 + lo;
                const u32 addr = (u32)(d * 128 + c * 64 + g * 16) ^ (u32)((d & 7) << 4);
                const short8 vf = *(const short8*)(Vtb + addr);
                oacc[n] = __builtin_amdgcn_mfma_f32_16x16x32_bf16(pf, vf, oacc[n], 0, 0, 0);
            }
        }

        // stage tile kt+1 (regs already loaded) into the other buffer; prefetch kt+2
        if (kt < 31) write_tile(cur ^ 1);
        if (kt < 30) load_tile(kt + 2);
        __syncthreads();
    }

    // finalize: O = q + oacc / l_run
#pragma unroll
    for (int r = 0; r < 4; ++r) {
        const float li = 1.0f / __shfl(l_run, (lane & 48) | (g * 4 + r));
        const size_t row = (size_t)(q0 + w * 16 + g * 4 + r);
#pragma unroll
        for (int n = 0; n < 4; ++n) {
            const int d = n * 16 + lo;
            const size_t idx = hbase + row * 256 + d;
            Obuf[idx] = oacc[n][r] * li + bf2f(qb[idx]);
        }
    }
}

// ---------------------------------------------------------------- LayerNorm (wave per 256-row)
// May run IN-PLACE (of == in): each lane reads its own float4 before writing it. No restrict.
template<bool WB>
__global__ __launch_bounds__(256)
void ln_kernel(const float* in, const float* __restrict__ gam,
               const float* __restrict__ bet, float* of,
               u16* __restrict__ ob) {
    const int w = threadIdx.x >> 6, lane = threadIdx.x & 63;
    const size_t row = (size_t)blockIdx.x * 4 + w;
    const float4 v = ((const float4*)(in + row * 256))[lane];
    float s = v.x + v.y + v.z + v.w;
    float q = v.x * v.x + v.y * v.y + v.z * v.z + v.w * v.w;
#pragma unroll
    for (int m = 1; m <= 32; m <<= 1) {
        s += __shfl_xor(s, m);
        q += __shfl_xor(q, m);
    }
    const float mu = s * (1.f / 256.f);
    const float var = q * (1.f / 256.f) - mu * mu;
    const float rstd = rsqrtf(var + 1e-5f);
    const float4 gv = ((const float4*)gam)[lane];
    const float4 bv = ((const float4*)bet)[lane];
    float4 y;
    y.x = (v.x - mu) * rstd * gv.x + bv.x;
    y.y = (v.y - mu) * rstd * gv.y + bv.y;
    y.z = (v.z - mu) * rstd * gv.z + bv.z;
    y.w = (v.w - mu) * rstd * gv.w + bv.w;
    ((float4*)(of + row * 256))[lane] = y;
    if (WB) {
        uint2 pk;
        pk.x = (u32)f2bf(y.x) | ((u32)f2bf(y.y) << 16);
        pk.y = (u32)f2bf(y.z) | ((u32)f2bf(y.w) << 16);
        *(uint2*)(ob + row * 256 + lane * 4) = pk;
    }
}

// ----------------------------------------------------------------------------------------------
// Workspace: Qc 8MB | Kc 8MB | qb 8MB | kbuf 8MB | vbuf 8MB | WT 0.5MB | bks — total ~40.6MB.
// Xb aliases Qc (dead after q-projection). Attention out / LN0 / MLP / LN1 chain in-place on d_out.
extern "C" void kernel_launch(void* const* d_in, const int* in_sizes, int n_in,
                              void* d_out, int out_size, void* d_ws, size_t ws_size,
                              hipStream_t stream) {
    const float* Q  = (const float*)d_in[0];
    const float* K  = (const float*)d_in[1];
    const float* Wq = (const float*)d_in[2];
    const float* bq = (const float*)d_in[3];
    const float* Wk = (const float*)d_in[4];
    const float* bk = (const float*)d_in[5];
    const float* Wv = (const float*)d_in[6];
    const float* bv = (const float*)d_in[7];
    const float* Wo = (const float*)d_in[8];
    const float* bo = (const float*)d_in[9];
    const float* g0 = (const float*)d_in[10];
    const float* be0 = (const float*)d_in[11];
    const float* g1 = (const float*)d_in[12];
    const float* be1 = (const float*)d_in[13];
    float* out = (float*)d_out;

    const size_t NE = (size_t)8 * 2048 * 256;  // 4,194,304
    char* ws = (char*)d_ws;
    size_t off = 0;
    auto alloc = [&](size_t bytes) { char* p = ws + off; off += (bytes + 255) & ~(size_t)255; return p; };
    u16* Qc   = (u16*)alloc(NE * 2);
    u16* Kc   = (u16*)alloc(NE * 2);
    u16* qb   = (u16*)alloc(NE * 2);
    u16* kbuf = (u16*)alloc(NE * 2);
    u16* vbuf = (u16*)alloc(NE * 2);
    u16* WT   = (u16*)alloc(4 * 65536 * 2);
    float* bks = (float*)alloc(256 * 4);
    u16* Xb   = Qc;          // alias: Qc dead after q-projection GEMM, Xb written by LN0 later
    float* Obuf = out;       // attention output lives in d_out; LN0/MLP/LN1 run in-place on it

    cvt2_kernel<<<4096, 256, 0, stream>>>(Q, K, Qc, Kc);
    wt_kernel<<<dim3(256, 4), 256, 0, stream>>>(Wq, Wk, Wv, Wo, bk, WT, bks);

    proj_kernel<<<dim3(128, 2, 3), 256, 0, stream>>>(Qc, Kc, WT, bq, bks, bv, qb, kbuf, vbuf);

    attn_kernel<<<dim3(16, 4, 8), 512, 0, stream>>>(qb, kbuf, vbuf, Obuf);

    ln_kernel<true><<<4096, 256, 0, stream>>>(Obuf, g0, be0, Obuf, Xb);       // in-place LN0
    mlp_kernel<<<dim3(128, 2), 256, 0, stream>>>(Xb, WT + 3 * 65536, bo, Obuf, Obuf); // in-place MLP
    ln_kernel<false><<<4096, 256, 0, stream>>>(Obuf, g1, be1, out, nullptr);  // in-place LN1
}